// Round 1
// baseline (227.796 us; speedup 1.0000x reference)
//
#include <hip/hip_runtime.h>

// bias = (1/nnz) * sum_e vals[e] * dot(x[rows[e]], x[cols[e]])
// N_FEAT = 128 floats = 32 float4 per row.

#define NFEAT4 32

__global__ __launch_bounds__(256, 4) void edge_dot_kernel(
    const float* __restrict__ x,
    const int* __restrict__ rows,
    const int* __restrict__ cols,
    const float* __restrict__ vals,
    float* __restrict__ partials,
    int nnz)
{
    const float4* __restrict__ x4 = reinterpret_cast<const float4*>(x);
    const int sub = threadIdx.x & 31;            // lane within 32-lane edge-group
    const int groupInBlock = threadIdx.x >> 5;   // 0..7 for 256 threads
    const int groupsPerBlock = blockDim.x >> 5;
    const long long gstride = (long long)gridDim.x * groupsPerBlock;
    long long e = (long long)blockIdx.x * groupsPerBlock + groupInBlock;

    float acc = 0.0f;
    for (; e < nnz; e += gstride) {
        const int r = rows[e];
        const int c = cols[e];
        const float v = vals[e];
        const float4 a = x4[(size_t)r * NFEAT4 + sub];
        const float4 b = x4[(size_t)c * NFEAT4 + sub];
        // Each lane keeps its partial of the dot; block reduction sums them.
        acc += v * (a.x * b.x + a.y * b.y + a.z * b.z + a.w * b.w);
    }

    // wave (64-lane) butterfly reduce
    #pragma unroll
    for (int m = 1; m < 64; m <<= 1)
        acc += __shfl_xor(acc, m);

    __shared__ float lds[4];
    const int lane = threadIdx.x & 63;
    const int wid  = threadIdx.x >> 6;
    if (lane == 0) lds[wid] = acc;
    __syncthreads();
    if (threadIdx.x == 0) {
        float s = 0.0f;
        const int nw = blockDim.x >> 6;
        for (int w = 0; w < nw; ++w) s += lds[w];
        partials[blockIdx.x] = s;
    }
}

__global__ __launch_bounds__(1024) void final_reduce_kernel(
    const float* __restrict__ partials, int n,
    float* __restrict__ out, float inv_nnz)
{
    float acc = 0.0f;
    for (int i = threadIdx.x; i < n; i += blockDim.x)
        acc += partials[i];
    #pragma unroll
    for (int m = 1; m < 64; m <<= 1)
        acc += __shfl_xor(acc, m);

    __shared__ float lds[16];
    const int lane = threadIdx.x & 63;
    const int wid  = threadIdx.x >> 6;
    if (lane == 0) lds[wid] = acc;
    __syncthreads();
    if (threadIdx.x == 0) {
        float s = 0.0f;
        const int nw = blockDim.x >> 6;
        for (int w = 0; w < nw; ++w) s += lds[w];
        out[0] = s * inv_nnz;
    }
}

extern "C" void kernel_launch(void* const* d_in, const int* in_sizes, int n_in,
                              void* d_out, int out_size, void* d_ws, size_t ws_size,
                              hipStream_t stream) {
    const float* x    = (const float*)d_in[0];
    const int*   rows = (const int*)d_in[1];
    const int*   cols = (const int*)d_in[2];
    const float* vals = (const float*)d_in[3];
    const int nnz = in_sizes[1];

    float* partials = (float*)d_ws;

    int grid = 2048;
    // clamp to workspace capacity (paranoia; ws is plenty big in practice)
    if ((size_t)grid * sizeof(float) > ws_size)
        grid = (int)(ws_size / sizeof(float));
    // also don't launch more groups than edges
    const int maxGroups = (nnz + 7) / 8;  // 8 groups of 32 lanes per block
    if (grid > maxGroups) grid = maxGroups;
    if (grid < 1) grid = 1;

    edge_dot_kernel<<<grid, 256, 0, stream>>>(x, rows, cols, vals, partials, nnz);

    final_reduce_kernel<<<1, 1024, 0, stream>>>(partials, grid, (float*)d_out,
                                                1.0f / (float)nnz);
}

// Round 2
// 118.995 us; speedup vs baseline: 1.9143x; 1.9143x over previous
//
#include <hip/hip_runtime.h>
#include <hip/hip_fp16.h>

// bias = (1/nnz) * sum_e vals[e] * dot(x[rows[e]], x[cols[e]])
// N_FEAT = 128.
// Strategy: convert x to fp16 once per call (halves random-gather bytes,
// which is the saturated resource), 16-lane groups do one edge each
// (256B row = 16 lanes x 16B), fp32 accumulate, deterministic two-stage
// block reduction.

#define NFEAT 128

struct h4pack { __half2 a, b; };  // 8 bytes = 4 halfs

__global__ __launch_bounds__(256) void convert_f2h_kernel(
    const float* __restrict__ x, h4pack* __restrict__ xh, int n4)
{
    const float4* __restrict__ x4 = reinterpret_cast<const float4*>(x);
    int i = blockIdx.x * blockDim.x + threadIdx.x;
    const int stride = gridDim.x * blockDim.x;
    for (; i < n4; i += stride) {
        float4 f = x4[i];
        h4pack p;
        p.a = __floats2half2_rn(f.x, f.y);
        p.b = __floats2half2_rn(f.z, f.w);
        xh[i] = p;
    }
}

__global__ __launch_bounds__(256) void edge_dot_h_kernel(
    const __half* __restrict__ xh,
    const int* __restrict__ rows,
    const int* __restrict__ cols,
    const float* __restrict__ vals,
    float* __restrict__ partials,
    int nnz)
{
    // 16B chunks of the fp16 row: row = 16 chunks of 8 halfs.
    const float4* __restrict__ xh4 = reinterpret_cast<const float4*>(xh);
    const int sub = threadIdx.x & 15;          // lane within 16-lane edge-group
    const int groupInBlock = threadIdx.x >> 4; // 0..15 for 256 threads
    const int groupsPerBlock = blockDim.x >> 4;
    const long long gstride = (long long)gridDim.x * groupsPerBlock;
    long long e = (long long)blockIdx.x * groupsPerBlock + groupInBlock;

    float acc = 0.0f;
    #pragma unroll 2
    for (; e < nnz; e += gstride) {
        const int r = rows[e];
        const int c = cols[e];
        const float v = vals[e];
        const float4 af = xh4[(size_t)r * 16 + sub];
        const float4 bf = xh4[(size_t)c * 16 + sub];
        const __half2* a2 = reinterpret_cast<const __half2*>(&af);
        const __half2* b2 = reinterpret_cast<const __half2*>(&bf);
        float d = 0.0f;
        #pragma unroll
        for (int k = 0; k < 4; ++k) {
            float2 fa = __half22float2(a2[k]);
            float2 fb = __half22float2(b2[k]);
            d += fa.x * fb.x + fa.y * fb.y;
        }
        acc += v * d;
    }

    // wave (64-lane) butterfly reduce
    #pragma unroll
    for (int m = 1; m < 64; m <<= 1)
        acc += __shfl_xor(acc, m);

    __shared__ float lds[4];
    const int lane = threadIdx.x & 63;
    const int wid  = threadIdx.x >> 6;
    if (lane == 0) lds[wid] = acc;
    __syncthreads();
    if (threadIdx.x == 0) {
        float s = 0.0f;
        const int nw = blockDim.x >> 6;
        for (int w = 0; w < nw; ++w) s += lds[w];
        partials[blockIdx.x] = s;
    }
}

// fp32 fallback (if workspace is too small for the fp16 shadow copy)
__global__ __launch_bounds__(256) void edge_dot_f_kernel(
    const float* __restrict__ x,
    const int* __restrict__ rows,
    const int* __restrict__ cols,
    const float* __restrict__ vals,
    float* __restrict__ partials,
    int nnz)
{
    const float4* __restrict__ x4 = reinterpret_cast<const float4*>(x);
    const int sub = threadIdx.x & 31;
    const int groupInBlock = threadIdx.x >> 5;
    const int groupsPerBlock = blockDim.x >> 5;
    const long long gstride = (long long)gridDim.x * groupsPerBlock;
    long long e = (long long)blockIdx.x * groupsPerBlock + groupInBlock;

    float acc = 0.0f;
    for (; e < nnz; e += gstride) {
        const int r = rows[e];
        const int c = cols[e];
        const float v = vals[e];
        const float4 a = x4[(size_t)r * 32 + sub];
        const float4 b = x4[(size_t)c * 32 + sub];
        acc += v * (a.x * b.x + a.y * b.y + a.z * b.z + a.w * b.w);
    }
    #pragma unroll
    for (int m = 1; m < 64; m <<= 1)
        acc += __shfl_xor(acc, m);

    __shared__ float lds[4];
    const int lane = threadIdx.x & 63;
    const int wid  = threadIdx.x >> 6;
    if (lane == 0) lds[wid] = acc;
    __syncthreads();
    if (threadIdx.x == 0) {
        float s = 0.0f;
        const int nw = blockDim.x >> 6;
        for (int w = 0; w < nw; ++w) s += lds[w];
        partials[blockIdx.x] = s;
    }
}

__global__ __launch_bounds__(1024) void final_reduce_kernel(
    const float* __restrict__ partials, int n,
    float* __restrict__ out, float inv_nnz)
{
    float acc = 0.0f;
    for (int i = threadIdx.x; i < n; i += blockDim.x)
        acc += partials[i];
    #pragma unroll
    for (int m = 1; m < 64; m <<= 1)
        acc += __shfl_xor(acc, m);

    __shared__ float lds[16];
    const int lane = threadIdx.x & 63;
    const int wid  = threadIdx.x >> 6;
    if (lane == 0) lds[wid] = acc;
    __syncthreads();
    if (threadIdx.x == 0) {
        float s = 0.0f;
        const int nw = blockDim.x >> 6;
        for (int w = 0; w < nw; ++w) s += lds[w];
        out[0] = s * inv_nnz;
    }
}

extern "C" void kernel_launch(void* const* d_in, const int* in_sizes, int n_in,
                              void* d_out, int out_size, void* d_ws, size_t ws_size,
                              hipStream_t stream) {
    const float* x    = (const float*)d_in[0];
    const int*   rows = (const int*)d_in[1];
    const int*   cols = (const int*)d_in[2];
    const float* vals = (const float*)d_in[3];
    const int nnz   = in_sizes[1];
    const int nfeat_total = in_sizes[0];          // N_NODES * 128
    const size_t xh_bytes = (size_t)nfeat_total * sizeof(__half);

    const int grid = 2048;
    const size_t need = xh_bytes + 256 + (size_t)grid * sizeof(float);

    if (ws_size >= need) {
        __half* xh = (__half*)d_ws;
        size_t poff = (xh_bytes + 255) & ~(size_t)255;
        float* partials = (float*)((char*)d_ws + poff);

        const int n4 = nfeat_total / 4;
        convert_f2h_kernel<<<2048, 256, 0, stream>>>(x, (h4pack*)d_ws, n4);

        int g = grid;
        const int maxGroups = (nnz + 15) / 16;
        if (g > maxGroups) g = maxGroups;
        if (g < 1) g = 1;
        edge_dot_h_kernel<<<g, 256, 0, stream>>>(xh, rows, cols, vals, partials, nnz);
        final_reduce_kernel<<<1, 1024, 0, stream>>>(partials, g, (float*)d_out,
                                                    1.0f / (float)nnz);
    } else {
        float* partials = (float*)d_ws;
        int g = grid;
        if ((size_t)g * sizeof(float) > ws_size) g = (int)(ws_size / sizeof(float));
        const int maxGroups = (nnz + 7) / 8;
        if (g > maxGroups) g = maxGroups;
        if (g < 1) g = 1;
        edge_dot_f_kernel<<<g, 256, 0, stream>>>(x, rows, cols, vals, partials, nnz);
        final_reduce_kernel<<<1, 1024, 0, stream>>>(partials, g, (float*)d_out,
                                                    1.0f / (float)nnz);
    }
}